// Round 1
// baseline (5453.137 us; speedup 1.0000x reference)
//
#include <hip/hip_runtime.h>
#include <stdint.h>

#define N_NODES 20000
#define E_EDGES 640000
#define F_IN    128
#define G_HID   128
#define L_HID   64
#define N_CLS   8
#define P_PATHS 4
#define SEQ_L   16
#define D_PATH  129
#define B_SEQ   (N_NODES * P_PATHS)

__device__ __forceinline__ float fsig(float x) { return 1.0f / (1.0f + __expf(-x)); }
__device__ __forceinline__ float ftanh(float x) { return 1.0f - 2.0f / (__expf(2.0f * x) + 1.0f); }

// ---------------- GCN ----------------

// deg[dst] += ew ; plus self-loop weight 1
__global__ void k_deg(const int* __restrict__ ei, const float* __restrict__ ea,
                      float* __restrict__ deg) {
    int i = blockIdx.x * blockDim.x + threadIdx.x;
    if (i < E_EDGES) {
        atomicAdd(&deg[ei[E_EDGES + i]], ea[i]);
    } else if (i < E_EDGES + N_NODES) {
        atomicAdd(&deg[i - E_EDGES], 1.0f);
    }
}

__global__ void k_dinv(const float* __restrict__ deg, float* __restrict__ dinv) {
    int i = blockIdx.x * blockDim.x + threadIdx.x;
    if (i < N_NODES) {
        float d = deg[i];
        dinv[i] = (d > 0.0f) ? rsqrtf(d) : 0.0f;
    }
}

__global__ void k_count(const int* __restrict__ ei, int* __restrict__ cnt) {
    int i = blockIdx.x * blockDim.x + threadIdx.x;
    if (i < E_EDGES) atomicAdd(&cnt[ei[E_EDGES + i]], 1);
}

// single-block exclusive scan over N_NODES counts
__global__ void k_scan(const int* __restrict__ cnt, int* __restrict__ rowstart) {
    __shared__ int part[1024];
    const int t = threadIdx.x;
    const int CH = 20;                       // 1024*20 >= 20000
    int begin = t * CH;
    int end = begin + CH; if (end > N_NODES) end = N_NODES;
    int s = 0;
    for (int j = begin; j < end && j < N_NODES; ++j) s += cnt[j];
    part[t] = s;
    __syncthreads();
    for (int off = 1; off < 1024; off <<= 1) {
        int v = (t >= off) ? part[t - off] : 0;
        __syncthreads();
        part[t] += v;
        __syncthreads();
    }
    int base = (t > 0) ? part[t - 1] : 0;
    for (int j = begin; j < end && j < N_NODES; ++j) { rowstart[j] = base; base += cnt[j]; }
    if (t == 1023) rowstart[N_NODES] = part[1023];
}

__global__ void k_fill(const int* __restrict__ ei, const float* __restrict__ ea,
                       const float* __restrict__ dinv, const int* __restrict__ rowstart,
                       int* __restrict__ fill, int* __restrict__ csr_src,
                       float* __restrict__ csr_w) {
    int i = blockIdx.x * blockDim.x + threadIdx.x;
    if (i < E_EDGES) {
        int s = ei[i];
        int d = ei[E_EDGES + i];
        float w = dinv[s] * ea[i] * dinv[d];
        int pos = rowstart[d] + atomicAdd(&fill[d], 1);
        csr_src[pos] = s;
        csr_w[pos]   = w;
    }
}

// xw = X @ Wg   (20000x128 @ 128x128) — 16 rows per 256-thread block
__global__ void k_xw(const float* __restrict__ X, const float* __restrict__ Wg,
                     float* __restrict__ xw) {
    __shared__ float Xs[16][128];
    const int t = threadIdx.x;
    const int c = t & 127;
    const int rg = t >> 7;                  // 0..1 -> rows rg*8 .. rg*8+7
    const int r0 = blockIdx.x * 16;
    for (int idx = t; idx < 16 * 128; idx += 256) {
        int row = idx >> 7, col = idx & 127;
        Xs[row][col] = X[(size_t)(r0 + row) * 128 + col];
    }
    __syncthreads();
    float acc[8];
#pragma unroll
    for (int j = 0; j < 8; ++j) acc[j] = 0.0f;
    for (int k = 0; k < 128; ++k) {
        float wv = Wg[k * 128 + c];
#pragma unroll
        for (int j = 0; j < 8; ++j) acc[j] = fmaf(Xs[rg * 8 + j][k], wv, acc[j]);
    }
#pragma unroll
    for (int j = 0; j < 8; ++j) xw[(size_t)(r0 + rg * 8 + j) * 128 + c] = acc[j];
}

// h0 = relu(self + neighbor aggregation + bg)
__global__ void k_aggr(const float* __restrict__ xw, const float* __restrict__ dinv,
                       const int* __restrict__ rowstart, const int* __restrict__ csr_src,
                       const float* __restrict__ csr_w, const float* __restrict__ bg,
                       float* __restrict__ h0) {
    const int n = blockIdx.x;
    const int f = threadIdx.x;              // 128 threads
    float di = dinv[n];
    float acc = di * di * xw[(size_t)n * 128 + f];
    int e0 = rowstart[n], e1 = rowstart[n + 1];
    for (int e = e0; e < e1; ++e) {
        acc = fmaf(csr_w[e], xw[(size_t)csr_src[e] * 128 + f], acc);
    }
    acc += bg[f];
    h0[(size_t)n * 128 + f] = fmaxf(acc, 0.0f);
}

// ---------------- LSTM prep: transpose weights to [dir][k][256] ----------------

__global__ void k_prep(const float* __restrict__ Wih_f, const float* __restrict__ Whh_f,
                       const float* __restrict__ bih_f, const float* __restrict__ bhh_f,
                       const float* __restrict__ Wih_b, const float* __restrict__ Whh_b,
                       const float* __restrict__ bih_b, const float* __restrict__ bhh_b,
                       float* __restrict__ Wih_t, float* __restrict__ Whh_t,
                       float* __restrict__ bias_c) {
    int i = blockIdx.x * blockDim.x + threadIdx.x;
    if (i < 2 * D_PATH * 256) {
        int d = i / (D_PATH * 256);
        int rem = i - d * (D_PATH * 256);
        int k = rem >> 8, g = rem & 255;
        const float* W = d ? Wih_b : Wih_f;
        Wih_t[i] = W[g * D_PATH + k];
    }
    int j = i - 2 * D_PATH * 256;
    if (j >= 0 && j < 2 * L_HID * 256) {
        int d = j / (L_HID * 256);
        int rem = j - d * (L_HID * 256);
        int k = rem >> 8, g = rem & 255;
        const float* W = d ? Whh_b : Whh_f;
        Whh_t[j] = W[g * L_HID + k];
    }
    int b = j - 2 * L_HID * 256;
    if (b >= 0 && b < 512) {
        int d = b >> 8, g = b & 255;
        bias_c[b] = d ? (bih_b[g] + bhh_b[g]) : (bih_f[g] + bhh_f[g]);
    }
}

// ---------------- LSTM main kernel ----------------
// grid (1250, 2): x = 64-sequence slab, y = direction.
// block 256 = 4 waves; wave w owns hidden units [w*16, w*16+16); lane = sequence.
// All weight reads wave-uniform -> scalar loads; only activations go through LDS.
__global__ __launch_bounds__(256, 2)
void k_lstm(const float* __restrict__ C,
            const float* __restrict__ Wih_t,   // [2][129][256]
            const float* __restrict__ Whh_t,   // [2][64][256]
            const float* __restrict__ bias_c,  // [2][256]
            float* __restrict__ hfin)          // [B_SEQ][128]
{
    __shared__ float xs[D_PATH * 65];
    __shared__ float hs[L_HID * 65];

    const int t    = threadIdx.x;
    const int lane = t & 63;
    const int w    = __builtin_amdgcn_readfirstlane(t >> 6);   // wave id 0..3 (SGPR)
    const int dir  = blockIdx.y;
    const int seq0 = blockIdx.x * 64;

    const float* Wih  = Wih_t + (size_t)dir * (D_PATH * 256);
    const float* Whh  = Whh_t + (size_t)dir * (L_HID * 256);
    const float* bias = bias_c + dir * 256 + w * 16;

    for (int i = t; i < L_HID * 65; i += 256) hs[i] = 0.0f;

    float c_st[16], hreg[16];
#pragma unroll
    for (int uu = 0; uu < 16; ++uu) { c_st[uu] = 0.0f; hreg[uu] = 0.0f; }

    const size_t crow = (size_t)seq0 * (SEQ_L * D_PATH);
    __syncthreads();

    for (int step = 0; step < SEQ_L; ++step) {
        const int l = dir ? (SEQ_L - 1 - step) : step;

        // stage x[l] for 64 sequences: layout xs[k][seq], row pad 65
        for (int idx = t; idx < 64 * D_PATH; idx += 256) {
            int s = idx / D_PATH;
            int k = idx - s * D_PATH;
            xs[k * 65 + s] = C[crow + (size_t)s * (SEQ_L * D_PATH) + (size_t)l * D_PATH + k];
        }
        __syncthreads();

        float acc[4][16];
#pragma unroll
        for (int q = 0; q < 4; ++q)
#pragma unroll
            for (int uu = 0; uu < 16; ++uu) acc[q][uu] = 0.0f;

        // input projection: K = 129
        for (int k = 0; k < D_PATH; ++k) {
            float xv = xs[k * 65 + lane];
            const float* wr = Wih + k * 256 + w * 16;   // wave-uniform -> s_load
#pragma unroll
            for (int q = 0; q < 4; ++q)
#pragma unroll
                for (int uu = 0; uu < 16; ++uu)
                    acc[q][uu] = fmaf(xv, wr[q * 64 + uu], acc[q][uu]);
        }
        // recurrence: K = 64
        for (int k = 0; k < L_HID; ++k) {
            float hv = hs[k * 65 + lane];
            const float* wr = Whh + k * 256 + w * 16;
#pragma unroll
            for (int q = 0; q < 4; ++q)
#pragma unroll
                for (int uu = 0; uu < 16; ++uu)
                    acc[q][uu] = fmaf(hv, wr[q * 64 + uu], acc[q][uu]);
        }
        __syncthreads();   // all hs reads complete before overwrite

        // gates: i,f,g,o per (unit, seq)
#pragma unroll
        for (int uu = 0; uu < 16; ++uu) {
            float iv = fsig (acc[0][uu] + bias[0 * 64 + uu]);
            float fv = fsig (acc[1][uu] + bias[1 * 64 + uu]);
            float gv = ftanh(acc[2][uu] + bias[2 * 64 + uu]);
            float ov = fsig (acc[3][uu] + bias[3 * 64 + uu]);
            float cc = fmaf(fv, c_st[uu], iv * gv);
            c_st[uu] = cc;
            float hh = ov * ftanh(cc);
            hreg[uu] = hh;
            hs[(w * 16 + uu) * 65 + lane] = hh;
        }
        __syncthreads();   // hs ready for next step
    }

    float* dst = hfin + (size_t)(seq0 + lane) * 128 + dir * 64 + w * 16;
#pragma unroll
    for (int v = 0; v < 4; ++v) {
        float4 o = make_float4(hreg[v * 4 + 0], hreg[v * 4 + 1],
                               hreg[v * 4 + 2], hreg[v * 4 + 3]);
        *(float4*)(dst + v * 4) = o;
    }
}

// ---------------- classifier ----------------
__global__ void k_final(const float* __restrict__ h0, const float* __restrict__ hfin,
                        const float* __restrict__ Wf, const float* __restrict__ bf,
                        float* __restrict__ out) {
    __shared__ float cat[256];
    __shared__ float ps[128];
    const int n = blockIdx.x, t = threadIdx.x;    // 128 threads
    cat[t] = h0[(size_t)n * 128 + t];
    const float* hp = hfin + (size_t)n * 512;
    cat[128 + t] = 0.25f * (hp[t] + hp[128 + t] + hp[256 + t] + hp[384 + t]);
    __syncthreads();
    int c = t & 7, pr = t >> 3;                   // 16 partial groups x 16 k
    float s = 0.0f;
    for (int k = pr * 16; k < pr * 16 + 16; ++k) s = fmaf(cat[k], Wf[k * 8 + c], s);
    ps[t] = s;
    __syncthreads();
    if (t < 8) {
        float r = bf[t];
        for (int p = 0; p < 16; ++p) r += ps[p * 8 + t];
        out[(size_t)n * 8 + t] = r;
    }
}

// ---------------- launch ----------------

extern "C" void kernel_launch(void* const* d_in, const int* in_sizes, int n_in,
                              void* d_out, int out_size, void* d_ws, size_t ws_size,
                              hipStream_t stream) {
    const float* X     = (const float*)d_in[0];
    const int*   ei    = (const int*)  d_in[1];
    const float* ea    = (const float*)d_in[2];
    const float* C     = (const float*)d_in[3];
    const float* Wg    = (const float*)d_in[4];
    const float* bg    = (const float*)d_in[5];
    const float* Wih_f = (const float*)d_in[6];
    const float* Whh_f = (const float*)d_in[7];
    const float* bih_f = (const float*)d_in[8];
    const float* bhh_f = (const float*)d_in[9];
    const float* Wih_b = (const float*)d_in[10];
    const float* Whh_b = (const float*)d_in[11];
    const float* bih_b = (const float*)d_in[12];
    const float* bhh_b = (const float*)d_in[13];
    const float* Wf    = (const float*)d_in[14];
    const float* bf    = (const float*)d_in[15];
    float* out = (float*)d_out;

    char* ws = (char*)d_ws;
    size_t cur = 0;
    auto alloc = [&](size_t bytes) -> void* {
        void* p = ws + cur;
        cur = (cur + bytes + 255) & ~(size_t)255;
        return p;
    };
    float* deg      = (float*)alloc((size_t)N_NODES * 4);
    float* dinv     = (float*)alloc((size_t)N_NODES * 4);
    int*   cnt      = (int*)  alloc((size_t)N_NODES * 4);
    int*   fill     = (int*)  alloc((size_t)N_NODES * 4);
    int*   rowstart = (int*)  alloc((size_t)(N_NODES + 1) * 4);
    int*   csr_src  = (int*)  alloc((size_t)E_EDGES * 4);
    float* csr_w    = (float*)alloc((size_t)E_EDGES * 4);
    float* xw       = (float*)alloc((size_t)N_NODES * 128 * 4);
    float* h0       = (float*)alloc((size_t)N_NODES * 128 * 4);
    float* Wih_t    = (float*)alloc((size_t)2 * D_PATH * 256 * 4);
    float* Whh_t    = (float*)alloc((size_t)2 * L_HID * 256 * 4);
    float* bias_c   = (float*)alloc((size_t)2 * 256 * 4);
    float* hfin     = (float*)alloc((size_t)B_SEQ * 128 * 4);

    hipMemsetAsync(deg,  0, (size_t)N_NODES * 4, stream);
    hipMemsetAsync(cnt,  0, (size_t)N_NODES * 4, stream);
    hipMemsetAsync(fill, 0, (size_t)N_NODES * 4, stream);

    // GCN
    k_deg  <<<(E_EDGES + N_NODES + 255) / 256, 256, 0, stream>>>(ei, ea, deg);
    k_dinv <<<(N_NODES + 255) / 256, 256, 0, stream>>>(deg, dinv);
    k_count<<<E_EDGES / 256, 256, 0, stream>>>(ei, cnt);
    k_scan <<<1, 1024, 0, stream>>>(cnt, rowstart);
    k_fill <<<E_EDGES / 256, 256, 0, stream>>>(ei, ea, dinv, rowstart, fill, csr_src, csr_w);
    k_xw   <<<N_NODES / 16, 256, 0, stream>>>(X, Wg, xw);
    k_aggr <<<N_NODES, 128, 0, stream>>>(xw, dinv, rowstart, csr_src, csr_w, bg, h0);

    // LSTM
    k_prep <<<(2 * D_PATH * 256 + 2 * L_HID * 256 + 512 + 255) / 256, 256, 0, stream>>>(
        Wih_f, Whh_f, bih_f, bhh_f, Wih_b, Whh_b, bih_b, bhh_b, Wih_t, Whh_t, bias_c);
    dim3 lg(B_SEQ / 64, 2);
    k_lstm <<<lg, 256, 0, stream>>>(C, Wih_t, Whh_t, bias_c, hfin);

    // classifier
    k_final<<<N_NODES, 128, 0, stream>>>(h0, hfin, Wf, bf, out);
}

// Round 4
// 1957.880 us; speedup vs baseline: 2.7852x; 2.7852x over previous
//
#include <hip/hip_runtime.h>
#include <stdint.h>

#define N_NODES 20000
#define E_EDGES 640000
#define F_IN    128
#define G_HID   128
#define L_HID   64
#define N_CLS   8
#define P_PATHS 4
#define SEQ_L   16
#define D_PATH  129
#define B_SEQ   (N_NODES * P_PATHS)

typedef __attribute__((ext_vector_type(8))) short bf16x8;
typedef __attribute__((ext_vector_type(4))) float f32x4;

__device__ __forceinline__ float fsig(float x) { return 1.0f / (1.0f + __expf(-x)); }
__device__ __forceinline__ float ftanh(float x) { return 1.0f - 2.0f / (__expf(2.0f * x) + 1.0f); }

__device__ __forceinline__ uint16_t f2bf(float f) {
    uint32_t u = __builtin_bit_cast(uint32_t, f);
    uint32_t r = u + 0x7FFFu + ((u >> 16) & 1u);
    return (uint16_t)(r >> 16);
}

// ---------------- GCN ----------------

__global__ void k_deg(const int* __restrict__ ei, const float* __restrict__ ea,
                      float* __restrict__ deg) {
    int i = blockIdx.x * blockDim.x + threadIdx.x;
    if (i < E_EDGES) {
        atomicAdd(&deg[ei[E_EDGES + i]], ea[i]);
    } else if (i < E_EDGES + N_NODES) {
        atomicAdd(&deg[i - E_EDGES], 1.0f);
    }
}

__global__ void k_dinv(const float* __restrict__ deg, float* __restrict__ dinv) {
    int i = blockIdx.x * blockDim.x + threadIdx.x;
    if (i < N_NODES) {
        float d = deg[i];
        dinv[i] = (d > 0.0f) ? rsqrtf(d) : 0.0f;
    }
}

__global__ void k_count(const int* __restrict__ ei, int* __restrict__ cnt) {
    int i = blockIdx.x * blockDim.x + threadIdx.x;
    if (i < E_EDGES) atomicAdd(&cnt[ei[E_EDGES + i]], 1);
}

__global__ void k_scan(const int* __restrict__ cnt, int* __restrict__ rowstart) {
    __shared__ int part[1024];
    const int t = threadIdx.x;
    const int CH = 20;
    int begin = t * CH;
    int end = begin + CH; if (end > N_NODES) end = N_NODES;
    int s = 0;
    for (int j = begin; j < end && j < N_NODES; ++j) s += cnt[j];
    part[t] = s;
    __syncthreads();
    for (int off = 1; off < 1024; off <<= 1) {
        int v = (t >= off) ? part[t - off] : 0;
        __syncthreads();
        part[t] += v;
        __syncthreads();
    }
    int base = (t > 0) ? part[t - 1] : 0;
    for (int j = begin; j < end && j < N_NODES; ++j) { rowstart[j] = base; base += cnt[j]; }
    if (t == 1023) rowstart[N_NODES] = part[1023];
}

__global__ void k_fill(const int* __restrict__ ei, const float* __restrict__ ea,
                       const float* __restrict__ dinv, const int* __restrict__ rowstart,
                       int* __restrict__ fill, int* __restrict__ csr_src,
                       float* __restrict__ csr_w) {
    int i = blockIdx.x * blockDim.x + threadIdx.x;
    if (i < E_EDGES) {
        int s = ei[i];
        int d = ei[E_EDGES + i];
        float w = dinv[s] * ea[i] * dinv[d];
        int pos = rowstart[d] + atomicAdd(&fill[d], 1);
        csr_src[pos] = s;
        csr_w[pos]   = w;
    }
}

__global__ void k_xw(const float* __restrict__ X, const float* __restrict__ Wg,
                     float* __restrict__ xw) {
    __shared__ float Xs[16][128];
    const int t = threadIdx.x;
    const int c = t & 127;
    const int rg = t >> 7;
    const int r0 = blockIdx.x * 16;
    for (int idx = t; idx < 16 * 128; idx += 256) {
        int row = idx >> 7, col = idx & 127;
        Xs[row][col] = X[(size_t)(r0 + row) * 128 + col];
    }
    __syncthreads();
    float acc[8];
#pragma unroll
    for (int j = 0; j < 8; ++j) acc[j] = 0.0f;
    for (int k = 0; k < 128; ++k) {
        float wv = Wg[k * 128 + c];
#pragma unroll
        for (int j = 0; j < 8; ++j) acc[j] = fmaf(Xs[rg * 8 + j][k], wv, acc[j]);
    }
#pragma unroll
    for (int j = 0; j < 8; ++j) xw[(size_t)(r0 + rg * 8 + j) * 128 + c] = acc[j];
}

// neighbor aggregation with 4-edge ILP
__global__ void k_aggr(const float* __restrict__ xw, const float* __restrict__ dinv,
                       const int* __restrict__ rowstart, const int* __restrict__ csr_src,
                       const float* __restrict__ csr_w, const float* __restrict__ bg,
                       float* __restrict__ h0) {
    const int n = blockIdx.x;
    const int f = threadIdx.x;
    float di = dinv[n];
    float acc = di * di * xw[(size_t)n * 128 + f];
    int e0 = rowstart[n], e1 = rowstart[n + 1];
    int e = e0;
    for (; e + 4 <= e1; e += 4) {
        int s0 = csr_src[e], s1 = csr_src[e + 1], s2 = csr_src[e + 2], s3 = csr_src[e + 3];
        float w0 = csr_w[e], w1 = csr_w[e + 1], w2 = csr_w[e + 2], w3 = csr_w[e + 3];
        float v0 = xw[(size_t)s0 * 128 + f];
        float v1 = xw[(size_t)s1 * 128 + f];
        float v2 = xw[(size_t)s2 * 128 + f];
        float v3 = xw[(size_t)s3 * 128 + f];
        acc = fmaf(w0, v0, acc); acc = fmaf(w1, v1, acc);
        acc = fmaf(w2, v2, acc); acc = fmaf(w3, v3, acc);
    }
    for (; e < e1; ++e) acc = fmaf(csr_w[e], xw[(size_t)csr_src[e] * 128 + f], acc);
    acc += bg[f];
    h0[(size_t)n * 128 + f] = fmaxf(acc, 0.0f);
}

// ---------------- LSTM weight prep: pack MFMA B-fragments (bf16) ----------------
// WihP layout: [d][w][kt(5)][q(4)][lane(64)][8]  (k padded 129->160, zeros beyond)
// WhhP layout: [d][w][kt(2)][q(4)][lane(64)][8]
// B-frag element j of lane l = W^T[k = kt*32 + (l>>4)*8 + j][n = q*64 + w*16 + (l&15)]
__global__ void k_prep(const float* __restrict__ Wih_f, const float* __restrict__ Whh_f,
                       const float* __restrict__ bih_f, const float* __restrict__ bhh_f,
                       const float* __restrict__ Wih_b, const float* __restrict__ Whh_b,
                       const float* __restrict__ bih_b, const float* __restrict__ bhh_b,
                       uint16_t* __restrict__ WihP, uint16_t* __restrict__ WhhP,
                       float* __restrict__ bias_c) {
    int fi = blockIdx.x * blockDim.x + threadIdx.x;
    if (fi < 81920) {                       // 2*4*5*4*64*8
        int j = fi & 7, lane = (fi >> 3) & 63, q = (fi >> 9) & 3;
        int rest = fi >> 11;                // 0..39 = d*20 + w*5 + kt
        int kt = rest % 5; int rest2 = rest / 5;
        int w = rest2 & 3, d = rest2 >> 2;
        int n = q * 64 + w * 16 + (lane & 15);
        int k = kt * 32 + ((lane >> 4) << 3) + j;
        const float* W = d ? Wih_b : Wih_f;
        float v = (k < D_PATH) ? W[n * D_PATH + k] : 0.0f;
        WihP[fi] = f2bf(v);
    } else if (fi < 114688) {               // + 2*4*2*4*64*8
        int fj = fi - 81920;
        int j = fj & 7, lane = (fj >> 3) & 63, q = (fj >> 9) & 3;
        int rest = fj >> 11;                // 0..15 = d*8 + w*2 + kt
        int kt = rest & 1, w = (rest >> 1) & 3, d = rest >> 3;
        int n = q * 64 + w * 16 + (lane & 15);
        int k = kt * 32 + ((lane >> 4) << 3) + j;
        const float* W = d ? Whh_b : Whh_f;
        WhhP[fj] = f2bf(W[n * L_HID + k]);
    } else if (fi < 115200) {
        int fb = fi - 114688;
        int d = fb >> 8, g = fb & 255;
        bias_c[fb] = d ? (bih_b[g] + bhh_b[g]) : (bih_f[g] + bhh_f[g]);
    }
}

// ---------------- LSTM main kernel (bf16 MFMA) ----------------
// Block = 256 thr = 4 waves, handles 64 sequences for one direction.
// Wave w owns units [w*16, w*16+16) across all 4 gates.
// Weights live in VGPRs for all 16 steps. x and h exchanged via swizzled bf16 LDS.
// LDS swizzle: element k of row s stored at k ^ ((s&7)<<3)  (16B-block XOR, T2).
#define XSTR 192
__global__ __launch_bounds__(256, 2)
void k_lstm(const float* __restrict__ C,
            const uint16_t* __restrict__ WihP,
            const uint16_t* __restrict__ WhhP,
            const float* __restrict__ bias_c,
            float* __restrict__ hfin)          // [B_SEQ][128] fp32
{
    __shared__ __align__(16) uint16_t xs[64 * XSTR];
    __shared__ __align__(16) uint16_t hs[64 * 64];

    const int t = threadIdx.x;
    const int l = t & 63;
    const int w = t >> 6;

    // bijective XCD swizzle (m204): nwg=2500 -> q=312, r=4; pairs (slab,dir0/1) adjacent
    int orig = blockIdx.x;
    int xcd = orig & 7;
    int i8  = orig >> 3;
    int wg  = (xcd < 4 ? xcd * 313 : 1252 + (xcd - 4) * 312) + i8;
    const int slab = wg >> 1;
    const int dir  = wg & 1;
    const int seq0 = slab * 64;

    // hoist weight fragments into VGPRs
    bf16x8 bih[5][4];
    bf16x8 bhh[2][4];
#pragma unroll
    for (int kt = 0; kt < 5; ++kt)
#pragma unroll
        for (int q = 0; q < 4; ++q)
            bih[kt][q] = *(const bf16x8*)(WihP + ((((dir * 4 + w) * 5 + kt) * 4 + q) * 64 + l) * 8);
#pragma unroll
    for (int kt = 0; kt < 2; ++kt)
#pragma unroll
        for (int q = 0; q < 4; ++q)
            bhh[kt][q] = *(const bf16x8*)(WhhP + ((((dir * 4 + w) * 2 + kt) * 4 + q) * 64 + l) * 8);

    float bias[4];
#pragma unroll
    for (int q = 0; q < 4; ++q)
        bias[q] = bias_c[dir * 256 + q * 64 + w * 16 + (l & 15)];

    // zero LDS (xs padding beyond k=128 must stay zero; hs = h_0 state)
    {
        uint32_t* p = (uint32_t*)xs;
        for (int i = t; i < (64 * XSTR) / 2; i += 256) p[i] = 0u;
        uint32_t* q = (uint32_t*)hs;
        for (int i = t; i < (64 * 64) / 2; i += 256) q[i] = 0u;
    }

    float c_st[4][4];
#pragma unroll
    for (int mi = 0; mi < 4; ++mi)
#pragma unroll
        for (int r = 0; r < 4; ++r) c_st[mi][r] = 0.0f;

    const float* Cb = C + (size_t)seq0 * (SEQ_L * D_PATH);
    const int ko  = (l >> 4) << 3;        // k-offset within tile for A-frags
    const int swz = (l & 7) << 3;         // row-swizzle for A-frag reads (seq&7 == l&7)

    __syncthreads();

    for (int step = 0; step < SEQ_L; ++step) {
        const int ll = dir ? (SEQ_L - 1 - step) : step;

        // (A) stage x[ll] -> xs (bf16, swizzled)
        const float* Cl = Cb + ll * D_PATH;
        for (int idx = t; idx < 64 * 32; idx += 256) {
            int s = idx >> 5; int c4 = (idx & 31) << 2;
            const float* p = Cl + (size_t)s * (SEQ_L * D_PATH) + c4;
            float v0 = p[0], v1 = p[1], v2 = p[2], v3 = p[3];
            int sw = (s & 7) << 3;
            uint32_t lo = (uint32_t)f2bf(v0) | ((uint32_t)f2bf(v1) << 16);
            uint32_t hi = (uint32_t)f2bf(v2) | ((uint32_t)f2bf(v3) << 16);
            *(uint2*)&xs[s * XSTR + (c4 ^ sw)] = make_uint2(lo, hi);
        }
        if (t < 64) {
            float v = Cl[(size_t)t * (SEQ_L * D_PATH) + 128];
            xs[t * XSTR + (128 ^ ((t & 7) << 3))] = f2bf(v);
        }
        __syncthreads();    // B1: xs ready, prev-step hs writes visible

        // (B) MFMA: acc[mi][q] = x @ Wih^T + h @ Whh^T   (fp32 accum)
        f32x4 acc[4][4];
#pragma unroll
        for (int mi = 0; mi < 4; ++mi)
#pragma unroll
            for (int q = 0; q < 4; ++q) acc[mi][q] = (f32x4)(0.0f);

#pragma unroll
        for (int kt = 0; kt < 5; ++kt) {
            bf16x8 a[4];
#pragma unroll
            for (int mi = 0; mi < 4; ++mi)
                a[mi] = *(const bf16x8*)&xs[(mi * 16 + (l & 15)) * XSTR + ((kt * 32 + ko) ^ swz)];
#pragma unroll
            for (int mi = 0; mi < 4; ++mi)
#pragma unroll
                for (int q = 0; q < 4; ++q)
                    acc[mi][q] = __builtin_amdgcn_mfma_f32_16x16x32_bf16(a[mi], bih[kt][q], acc[mi][q], 0, 0, 0);
        }
#pragma unroll
        for (int kt = 0; kt < 2; ++kt) {
            bf16x8 a[4];
#pragma unroll
            for (int mi = 0; mi < 4; ++mi)
                a[mi] = *(const bf16x8*)&hs[(mi * 16 + (l & 15)) * 64 + ((kt * 32 + ko) ^ swz)];
#pragma unroll
            for (int mi = 0; mi < 4; ++mi)
#pragma unroll
                for (int q = 0; q < 4; ++q)
                    acc[mi][q] = __builtin_amdgcn_mfma_f32_16x16x32_bf16(a[mi], bhh[kt][q], acc[mi][q], 0, 0, 0);
        }
        __syncthreads();    // B2: all LDS reads done -> safe to overwrite hs / xs

        // (C) gates. C/D layout: col(l&15)=unit, row=(l>>4)*4+r=seq within mi-tile.
        const bool last = (step == SEQ_L - 1);
#pragma unroll
        for (int mi = 0; mi < 4; ++mi)
#pragma unroll
            for (int r = 0; r < 4; ++r) {
                float iv = fsig (acc[mi][0][r] + bias[0]);
                float fv = fsig (acc[mi][1][r] + bias[1]);
                float gv = ftanh(acc[mi][2][r] + bias[2]);
                float ov = fsig (acc[mi][3][r] + bias[3]);
                float cc = fmaf(fv, c_st[mi][r], iv * gv);
                c_st[mi][r] = cc;
                float hh = ov * ftanh(cc);
                int seq = mi * 16 + ((l >> 4) << 2) + r;
                if (!last) {
                    hs[seq * 64 + ((w * 16 + (l & 15)) ^ ((seq & 7) << 3))] = f2bf(hh);
                } else {
                    hfin[(size_t)(seq0 + seq) * 128 + dir * 64 + w * 16 + (l & 15)] = hh;
                }
            }
        // loop: (A) writes xs only (safe after B2); B1 publishes hs for next (B)
    }
}

// ---------------- classifier ----------------
__global__ void k_final(const float* __restrict__ h0, const float* __restrict__ hfin,
                        const float* __restrict__ Wf, const float* __restrict__ bf,
                        float* __restrict__ out) {
    __shared__ float cat[256];
    __shared__ float ps[128];
    const int n = blockIdx.x, t = threadIdx.x;
    cat[t] = h0[(size_t)n * 128 + t];
    const float* hp = hfin + (size_t)n * 512;
    cat[128 + t] = 0.25f * (hp[t] + hp[128 + t] + hp[256 + t] + hp[384 + t]);
    __syncthreads();
    int c = t & 7, pr = t >> 3;
    float s = 0.0f;
    for (int k = pr * 16; k < pr * 16 + 16; ++k) s = fmaf(cat[k], Wf[k * 8 + c], s);
    ps[t] = s;
    __syncthreads();
    if (t < 8) {
        float r = bf[t];
        for (int p = 0; p < 16; ++p) r += ps[p * 8 + t];
        out[(size_t)n * 8 + t] = r;
    }
}

// ---------------- launch ----------------

extern "C" void kernel_launch(void* const* d_in, const int* in_sizes, int n_in,
                              void* d_out, int out_size, void* d_ws, size_t ws_size,
                              hipStream_t stream) {
    const float* X     = (const float*)d_in[0];
    const int*   ei    = (const int*)  d_in[1];
    const float* ea    = (const float*)d_in[2];
    const float* C     = (const float*)d_in[3];
    const float* Wg    = (const float*)d_in[4];
    const float* bg    = (const float*)d_in[5];
    const float* Wih_f = (const float*)d_in[6];
    const float* Whh_f = (const float*)d_in[7];
    const float* bih_f = (const float*)d_in[8];
    const float* bhh_f = (const float*)d_in[9];
    const float* Wih_b = (const float*)d_in[10];
    const float* Whh_b = (const float*)d_in[11];
    const float* bih_b = (const float*)d_in[12];
    const float* bhh_b = (const float*)d_in[13];
    const float* Wf    = (const float*)d_in[14];
    const float* bf    = (const float*)d_in[15];
    float* out = (float*)d_out;

    char* ws = (char*)d_ws;
    size_t cur = 0;
    auto alloc = [&](size_t bytes) -> void* {
        void* p = ws + cur;
        cur = (cur + bytes + 255) & ~(size_t)255;
        return p;
    };
    float*    deg      = (float*)   alloc((size_t)N_NODES * 4);
    float*    dinv     = (float*)   alloc((size_t)N_NODES * 4);
    int*      cnt      = (int*)     alloc((size_t)N_NODES * 4);
    int*      fill     = (int*)     alloc((size_t)N_NODES * 4);
    int*      rowstart = (int*)     alloc((size_t)(N_NODES + 1) * 4);
    int*      csr_src  = (int*)     alloc((size_t)E_EDGES * 4);
    float*    csr_w    = (float*)   alloc((size_t)E_EDGES * 4);
    float*    xw       = (float*)   alloc((size_t)N_NODES * 128 * 4);
    float*    h0       = (float*)   alloc((size_t)N_NODES * 128 * 4);
    uint16_t* WihP     = (uint16_t*)alloc((size_t)81920 * 2);
    uint16_t* WhhP     = (uint16_t*)alloc((size_t)32768 * 2);
    float*    bias_c   = (float*)   alloc((size_t)512 * 4);
    float*    hfin     = (float*)   alloc((size_t)B_SEQ * 128 * 4);

    hipMemsetAsync(deg,  0, (size_t)N_NODES * 4, stream);
    hipMemsetAsync(cnt,  0, (size_t)N_NODES * 4, stream);
    hipMemsetAsync(fill, 0, (size_t)N_NODES * 4, stream);

    // GCN
    k_deg  <<<(E_EDGES + N_NODES + 255) / 256, 256, 0, stream>>>(ei, ea, deg);
    k_dinv <<<(N_NODES + 255) / 256, 256, 0, stream>>>(deg, dinv);
    k_count<<<E_EDGES / 256, 256, 0, stream>>>(ei, cnt);
    k_scan <<<1, 1024, 0, stream>>>(cnt, rowstart);
    k_fill <<<E_EDGES / 256, 256, 0, stream>>>(ei, ea, dinv, rowstart, fill, csr_src, csr_w);
    k_xw   <<<N_NODES / 16, 256, 0, stream>>>(X, Wg, xw);
    k_aggr <<<N_NODES, 128, 0, stream>>>(xw, dinv, rowstart, csr_src, csr_w, bg, h0);

    // LSTM
    k_prep <<<(115200 + 255) / 256, 256, 0, stream>>>(
        Wih_f, Whh_f, bih_f, bhh_f, Wih_b, Whh_b, bih_b, bhh_b, WihP, WhhP, bias_c);
    k_lstm <<<2500, 256, 0, stream>>>(C, WihP, WhhP, bias_c, hfin);

    // classifier
    k_final<<<N_NODES, 128, 0, stream>>>(h0, hfin, Wf, bf, out);
}